// Round 10
// baseline (659.878 us; speedup 1.0000x reference)
//
#include <hip/hip_runtime.h>
#include <stdint.h>

typedef unsigned int u32;
typedef unsigned short u16;
typedef unsigned char u8;

typedef __attribute__((ext_vector_type(4))) float f32x4;
typedef __attribute__((ext_vector_type(8))) __bf16 bf16x8;

#define NN 100000
#define NE 1600000
#define NSLICE 8
#define SLICE_NODES 12500   // NN / NSLICE exactly

typedef __attribute__((address_space(1))) u32 ga_u32;
typedef __attribute__((address_space(3))) u32 ls_u32;

static __device__ __forceinline__ u32 f2bf_bits(float f){
  u32 u = __float_as_uint(f);
  return (u + 0x7fffu + ((u >> 16) & 1u)) >> 16;   // RNE f32->bf16
}

// f32 -> fp8 e4m3fn (OCP): FTZ below 2^-6, RNE to 3 mantissa bits, clamp 448
static __device__ __forceinline__ u32 f2fp8(float f){
  u32 b = __float_as_uint(f);
  u32 s = (b >> 24) & 0x80u;
  u32 a = b & 0x7fffffffu;
  if (a < 0x3c800000u) return s;                  // |f| < 2^-6 -> signed zero
  u32 r = a + 0x7ffffu + ((a >> 20) & 1u);        // RNE at bit 20
  u32 code = (r >> 20) - 0x3c0u;                  // (e32-120)<<3 | m3
  if (code > 0x7eu) code = 0x7eu;                 // clamp to 448 (no inf in e4m3fn)
  return s | code;
}

// accumulate 4 fp8 (one dword) into a[0..3]
static __device__ __forceinline__ void acc_fp8x4(float* a, u32 w){
#if __has_builtin(__builtin_amdgcn_cvt_pk_f32_fp8)
  auto lo = __builtin_amdgcn_cvt_pk_f32_fp8(w, false);   // bytes 0,1
  auto hi = __builtin_amdgcn_cvt_pk_f32_fp8(w, true);    // bytes 2,3
  a[0] += lo[0]; a[1] += lo[1]; a[2] += hi[0]; a[3] += hi[1];
#else
  #pragma unroll
  for (int k = 0; k < 4; k++){
    u32 x = (w >> (8*k)) & 0xffu;
    u32 v = ((x & 0x80u) << 24) | (((x & 0x7fu) << 20) + 0x3c000000u);
    a[k] += (x & 0x7fu) ? __uint_as_float(v) : 0.f;
  }
#endif
}
static __device__ __forceinline__ void acc16(float* a, uint4 w){
  acc_fp8x4(a,     w.x); acc_fp8x4(a + 4, w.y);
  acc_fp8x4(a + 8, w.z); acc_fp8x4(a + 12, w.w);
}

static __device__ __forceinline__ void gload16(const void* g, void* l){
  __builtin_amdgcn_global_load_lds((const ga_u32*)g, (ls_u32*)l, 16, 0, 0);
}

// ---------------- CSR build (counting sort by dst) ----------------
__global__ void k_hist(const int* __restrict__ dst, int* __restrict__ cnt){
  int e = blockIdx.x*256 + threadIdx.x;
  if (e < NE) atomicAdd(&cnt[dst[e]], 1);
}

__global__ void k_scan1(const int* __restrict__ cnt, int* __restrict__ excl, int* __restrict__ bsum){
  __shared__ int s[1024];
  int t = threadIdx.x;
  int i = blockIdx.x*1024 + t;
  int v = (i < NN) ? cnt[i] : 0;
  s[t] = v; __syncthreads();
  int acc = v;
  for (int off = 1; off < 1024; off <<= 1){
    int tmp = (t >= off) ? s[t-off] : 0;
    __syncthreads();
    acc += tmp; s[t] = acc;
    __syncthreads();
  }
  if (i < NN) excl[i] = acc - v;           // block-local exclusive
  if (t == 1023) bsum[blockIdx.x] = acc;   // block total
}

__global__ void k_scan2(int* bsum, int nb){
  if (threadIdx.x == 0 && blockIdx.x == 0){
    int run = 0;
    for (int b = 0; b < nb; b++){ int t = bsum[b]; bsum[b] = run; run += t; }
  }
}

__global__ void k_scan3(const int* __restrict__ cnt, int* __restrict__ row_start,
                        const int* __restrict__ bsum, int* __restrict__ fill_ptr,
                        float* __restrict__ rdeg){
  int i = blockIdx.x*256 + threadIdx.x;
  if (i >= NN) return;
  int rs = row_start[i] + bsum[i >> 10];
  row_start[i] = rs;
  fill_ptr[i]  = rs;
  int c = cnt[i];
  rdeg[i] = 1.0f / (float)(c > 1 ? c : 1);
}

// dst-sliced fill: slice = blockIdx&7 -> one XCD's L2 owns each slice's lines.
__global__ __launch_bounds__(256) void k_fill(const int* __restrict__ src,
    const int* __restrict__ dst, int* __restrict__ fill_ptr, int* __restrict__ ssrc){
  int slice = blockIdx.x & 7;
  int bin   = blockIdx.x >> 3;
  int nbin  = gridDim.x >> 3;
  int lo = slice * SLICE_NODES;
  int hi = lo + SLICE_NODES;
  for (int e = bin*256 + threadIdx.x; e < NE; e += nbin*256){
    int d = dst[e];
    if (d >= lo && d < hi){
      int pos = atomicAdd(&fill_ptr[d], 1);
      ssrc[pos] = src[e];
    }
  }
}

// ---------------- weight prep: transpose to [N][K] bf16, K-concat [Wl;Wr] ----------------
__global__ void k_wprep(const float* __restrict__ Wl0, const float* __restrict__ Wr0,
                        const float* __restrict__ Wl1, const float* __restrict__ Wr1,
                        const float* __restrict__ Wl2, const float* __restrict__ Wr2,
                        u16* __restrict__ W1t, u16* __restrict__ W2t, u16* __restrict__ W3t){
  int idx = blockIdx.x*256 + threadIdx.x;
  if (idx < 256*256){                       // W1t [256][256]: k<128 Wl0, else Wr0
    int n = idx >> 8, k = idx & 255;
    float v = (k < 128) ? Wl0[k*256 + n] : Wr0[(k-128)*256 + n];
    W1t[idx] = (u16)f2bf_bits(v);
  } else if (idx < 256*256 + 256*512){      // W2t [256][512]: k<256 Wl1, else Wr1
    int j = idx - 256*256;
    int n = j >> 9, k = j & 511;
    float v = (k < 256) ? Wl1[k*256 + n] : Wr1[(k-256)*256 + n];
    W2t[j] = (u16)f2bf_bits(v);
  } else {                                  // W3t [128][256]: n<47 Wl2 (->Gl), n 64..110 Wr2 (->Gr)
    int j = idx - (256*256 + 256*512);
    int n = j >> 8, k = j & 255;
    float v = 0.f;
    if (n < 47) v = Wl2[k*47 + n];
    else if (n >= 64 && n < 111) v = Wr2[k*47 + (n-64)];
    W3t[j] = (u16)f2bf_bits(v);
  }
}

// x f32 -> xb bf16 (GEMM1 root operand) + xb8 fp8 (layer-1 gather table)
__global__ void k_xconv(const float* __restrict__ x, u16* __restrict__ xb,
                        u8* __restrict__ xb8){
  int i = blockIdx.x*256 + threadIdx.x;     // 4 floats per thread
  if (i >= NN*128/4) return;
  const float4* xp = (const float4*)x;
  float4 v = xp[i];
  u32 lo = f2bf_bits(v.x) | (f2bf_bits(v.y) << 16);
  u32 hi = f2bf_bits(v.z) | (f2bf_bits(v.w) << 16);
  ((u32*)xb)[2*i]   = lo;
  ((u32*)xb)[2*i+1] = hi;
  ((u32*)xb8)[i] = f2fp8(v.x) | (f2fp8(v.y) << 8) | (f2fp8(v.z) << 16) | (f2fp8(v.w) << 24);
}

// ---------------- mean aggregation over fp8 table: 1 wave/node ----------------
// Row = F fp8 bytes. LPR = F/16 lanes per row (16B dwordx4 each); G = 64/LPR rows
// per load instruction (F=256 -> 4, F=128 -> 8). UN supersteps in flight.
// Accumulate f32, reduce across subs via shfl, write agg row as bf16.
template<int F, int UN>
__global__ __launch_bounds__(256) void k_agg8(const u8* __restrict__ feat,
    const int* __restrict__ row_start, const int* __restrict__ cnt,
    const float* __restrict__ rdeg, const int* __restrict__ ssrc,
    u16* __restrict__ out){
  constexpr int LPR = F/16;       // lanes per row
  constexpr int G   = 64/LPR;     // rows per load instr
  int i = blockIdx.x*4 + (threadIdx.x >> 6);
  if (i >= NN) return;
  int lane = threadIdx.x & 63;
  int lir  = lane & (LPR-1);
  int sub  = lane / LPR;          // 0..G-1
  const u8* base = feat + lir*16;
  int beg = row_start[i], num = cnt[i];
  float a[16];
  #pragma unroll
  for (int k = 0; k < 16; k++) a[k] = 0.f;
  int j = 0;
  for (; j + G*UN <= num; j += G*UN){       // UN 16B loads in flight
    uint4 w[UN];
    #pragma unroll
    for (int u = 0; u < UN; u++)
      w[u] = *(const uint4*)(base + (size_t)ssrc[beg + j + u*G + sub]*F);
    #pragma unroll
    for (int u = 0; u < UN; u++) acc16(a, w[u]);
  }
  for (; j + G <= num; j += G){             // G-row tail
    uint4 w = *(const uint4*)(base + (size_t)ssrc[beg + j + sub]*F);
    acc16(a, w);
  }
  int rem = num - j;                        // 0..G-1 leftover rows
  if (rem > 0){
    int idx = ssrc[beg + j + (sub < rem ? sub : 0)];
    uint4 w = *(const uint4*)(base + (size_t)idx*F);
    if (sub < rem) acc16(a, w);
  }
  #pragma unroll
  for (int k = 0; k < 16; k++)
    for (int off = LPR; off < 64; off <<= 1)
      a[k] += __shfl_xor(a[k], off, 64);
  if (sub == 0){
    float r = rdeg[i];
    uint4 p0, p1;
    p0.x = f2bf_bits(a[0]*r)  | (f2bf_bits(a[1]*r)  << 16);
    p0.y = f2bf_bits(a[2]*r)  | (f2bf_bits(a[3]*r)  << 16);
    p0.z = f2bf_bits(a[4]*r)  | (f2bf_bits(a[5]*r)  << 16);
    p0.w = f2bf_bits(a[6]*r)  | (f2bf_bits(a[7]*r)  << 16);
    p1.x = f2bf_bits(a[8]*r)  | (f2bf_bits(a[9]*r)  << 16);
    p1.y = f2bf_bits(a[10]*r) | (f2bf_bits(a[11]*r) << 16);
    p1.z = f2bf_bits(a[12]*r) | (f2bf_bits(a[13]*r) << 16);
    p1.w = f2bf_bits(a[14]*r) | (f2bf_bits(a[15]*r) << 16);
    u16* op = out + (size_t)i*F + lir*16;
    *(uint4*)(op)     = p0;
    *(uint4*)(op + 8) = p1;
  }
}

// ---------------- bf16 MFMA GEMM, 128x128 tile, BK=64, dual-A (K-concat) ----------------
// If C2 != nullptr: split write, cols 0..63 -> C (ldc 64), cols 64..127 -> C2 (ldc 64).
// If F8 != nullptr: additionally store e4m3 of the (activated) value at [row*ldc+col].
template<bool RELU>
__global__ __launch_bounds__(256) void k_gemm(
    const u16* __restrict__ A1, int K1, const u16* __restrict__ A2, int K2,
    const u16* __restrict__ Bt, const float* __restrict__ bias,
    u16* __restrict__ C, int ldc, u16* __restrict__ C2, u8* __restrict__ F8){
  __shared__ u16 As[128*64];
  __shared__ u16 Bs[128*64];
  const int M = NN;
  const int K = K1 + K2;
  const int gm = (M + 127) >> 7;
  int bm = blockIdx.x % gm, bn = blockIdx.x / gm;
  int tid = threadIdx.x;
  int lane = tid & 63, w = tid >> 6;
  int wm = w >> 1, wn = w & 1;               // 4 waves = 2x2, 64x64 each
  int lr = lane & 15, l4 = lane >> 4;
  f32x4 acc[4][4] = {};
  const int nk = K >> 6;
  for (int kstep = 0; kstep < nk; kstep++){
    __syncthreads();
    #pragma unroll
    for (int q = 0; q < 4; q++){
      int L = q*4096 + tid*16;                // linear LDS dest (gload_lds requirement)
      int row = L >> 7;                       // 128B per row (64 bf16)
      int c16 = ((L >> 4) & 7) ^ (row & 7);   // inverse-swizzled SOURCE
      int gk = (kstep << 6) + (c16 << 3);
      int grow = bm*128 + row; if (grow >= M) grow = M - 1;
      const u16* ga = (gk < K1) ? (A1 + (size_t)grow*K1 + gk)
                                : (A2 + (size_t)grow*K2 + (gk - K1));
      gload16(ga, (char*)As + L);
      int gcol = bn*128 + row;
      gload16(Bt + (size_t)gcol*K + gk, (char*)Bs + L);
    }
    __syncthreads();
    #pragma unroll
    for (int kk = 0; kk < 2; kk++){
      bf16x8 af[4], bf[4];
      #pragma unroll
      for (int fm = 0; fm < 4; fm++){
        int row = wm*64 + fm*16 + lr;
        int c16 = (kk << 2) + l4;
        af[fm] = *(const bf16x8*)((const char*)As + row*128 + ((c16 ^ (row&7)) << 4));
      }
      #pragma unroll
      for (int fn = 0; fn < 4; fn++){
        int row = wn*64 + fn*16 + lr;
        int c16 = (kk << 2) + l4;
        bf[fn] = *(const bf16x8*)((const char*)Bs + row*128 + ((c16 ^ (row&7)) << 4));
      }
      #pragma unroll
      for (int fm = 0; fm < 4; fm++)
        #pragma unroll
        for (int fn = 0; fn < 4; fn++)
          acc[fm][fn] = __builtin_amdgcn_mfma_f32_16x16x32_bf16(af[fm], bf[fn], acc[fm][fn], 0, 0, 0);
    }
  }
  #pragma unroll
  for (int fn = 0; fn < 4; fn++){
    int col = bn*128 + wn*64 + fn*16 + lr;
    float bv = bias ? bias[col] : 0.f;
    #pragma unroll
    for (int fm = 0; fm < 4; fm++){
      #pragma unroll
      for (int q = 0; q < 4; q++){
        int rowg = bm*128 + wm*64 + fm*16 + l4*4 + q;
        if (rowg < M){
          float v = acc[fm][fn][q] + bv;
          if (RELU) v = fmaxf(v, 0.f);
          u16* cp;
          if (C2 == nullptr) cp = C + (size_t)rowg*ldc + col;
          else cp = (col < 64) ? C  + (size_t)rowg*64 + col
                               : C2 + (size_t)rowg*64 + (col - 64);
          *cp = (u16)f2bf_bits(v);
          if (F8) F8[(size_t)rowg*ldc + col] = (u8)f2fp8(v);
        }
      }
    }
  }
}

// ---------------- layer3 tail: agg(Gl) + Gr(root) + b2 + log_softmax ----------------
// half-wave (32 lanes) per node; lane t owns features 2t, 2t+1 (valid < 47)
__global__ __launch_bounds__(256) void k_final(const u16* __restrict__ Gl,
    const u16* __restrict__ Gr, const int* __restrict__ row_start,
    const int* __restrict__ cnt, const float* __restrict__ rdeg,
    const int* __restrict__ ssrc, const float* __restrict__ b2,
    float* __restrict__ out){
  int i = blockIdx.x*8 + (threadIdx.x >> 5);
  if (i >= NN) return;
  int t = threadIdx.x & 31;
  int beg = row_start[i], num = cnt[i];
  const u16* gp = Gl + 2*t;                  // cols 2t, 2t+1 (<=63, in-bounds)
  float a = 0.f, b = 0.f;
  int j = 0;
  for (; j + 4 <= num; j += 4){
    u32 w[4];
    #pragma unroll
    for (int u = 0; u < 4; u++) w[u] = *(const u32*)(gp + (size_t)ssrc[beg+j+u]*64);
    #pragma unroll
    for (int u = 0; u < 4; u++){ a += __uint_as_float(w[u] << 16); b += __uint_as_float(w[u] & 0xffff0000u); }
  }
  for (; j < num; j++){
    u32 w = *(const u32*)(gp + (size_t)ssrc[beg+j]*64);
    a += __uint_as_float(w << 16); b += __uint_as_float(w & 0xffff0000u);
  }
  float r = rdeg[i];
  u32 rw = *(const u32*)(Gr + (size_t)i*64 + 2*t);  // root cols 2t, 2t+1
  int f0 = 2*t, f1 = 2*t + 1;
  float va = (f0 < 47) ? a*r + __uint_as_float(rw << 16)          + b2[f0] : -3.0e38f;
  float vb = (f1 < 47) ? b*r + __uint_as_float(rw & 0xffff0000u)  + b2[f1] : -3.0e38f;
  float m = fmaxf(va, vb);
  #pragma unroll
  for (int o = 16; o > 0; o >>= 1) m = fmaxf(m, __shfl_xor(m, o, 32));
  float e = 0.f;
  if (f0 < 47) e += expf(va - m);
  if (f1 < 47) e += expf(vb - m);
  float s = e;
  #pragma unroll
  for (int o = 16; o > 0; o >>= 1) s += __shfl_xor(s, o, 32);
  float ls = logf(s);
  if (f0 < 47) out[(size_t)i*47 + f0] = va - m - ls;
  if (f1 < 47) out[(size_t)i*47 + f1] = vb - m - ls;
}

// ---------------- launcher ----------------
extern "C" void kernel_launch(void* const* d_in, const int* in_sizes, int n_in,
                              void* d_out, int out_size, void* d_ws, size_t ws_size,
                              hipStream_t stream){
  const float* x   = (const float*)d_in[0];
  const int*   src = (const int*)d_in[1];
  const int*   dst = (const int*)d_in[2];
  const float* Wl0 = (const float*)d_in[3];
  const float* Wr0 = (const float*)d_in[4];
  const float* b0  = (const float*)d_in[5];
  const float* Wl1 = (const float*)d_in[6];
  const float* Wr1 = (const float*)d_in[7];
  const float* b1  = (const float*)d_in[8];
  const float* Wl2 = (const float*)d_in[9];
  const float* Wr2 = (const float*)d_in[10];
  const float* b2  = (const float*)d_in[11];
  float* out = (float*)d_out;

  char* p = (char*)d_ws;
  size_t off = 0;
  auto alloc = [&](size_t bytes)->char*{
    char* r = p + off; off += (bytes + 511) & ~((size_t)511); return r;
  };
  int*   cnt       = (int*)  alloc((size_t)NN*4);
  int*   row_start = (int*)  alloc((size_t)NN*4);
  int*   fill_ptr  = (int*)  alloc((size_t)NN*4);
  float* rdeg      = (float*)alloc((size_t)NN*4);
  int*   bsum      = (int*)  alloc(512);
  int*   ssrc      = (int*)  alloc((size_t)NE*4);
  u16*   W1t       = (u16*)  alloc((size_t)256*256*2);
  u16*   W2t       = (u16*)  alloc((size_t)256*512*2);
  u16*   W3t       = (u16*)  alloc((size_t)128*256*2);
  u16*   xb        = (u16*)  alloc((size_t)NN*128*2);  // reused as Gl|Gr after GEMM3
  u8*    xb8       = (u8*)   alloc((size_t)NN*128);
  u8*    h1f8      = (u8*)   alloc((size_t)NN*256);
  u16*   agg1      = (u16*)  alloc((size_t)NN*128*2);
  u16*   h1        = (u16*)  alloc((size_t)NN*256*2);
  u16*   agg2      = (u16*)  alloc((size_t)NN*256*2);
  u16*   h2        = (u16*)  alloc((size_t)NN*256*2);
  u16*   Gl = xb;
  u16*   Gr = xb + (size_t)NN*64;

  const int nb_scan = (NN + 1023) / 1024;

  hipMemsetAsync(cnt, 0, (size_t)NN*4, stream);
  k_hist <<<NE/256, 256, 0, stream>>>(dst, cnt);
  k_scan1<<<nb_scan, 1024, 0, stream>>>(cnt, row_start, bsum);
  k_scan2<<<1, 64, 0, stream>>>(bsum, nb_scan);
  k_scan3<<<(NN+255)/256, 256, 0, stream>>>(cnt, row_start, bsum, fill_ptr, rdeg);
  k_fill <<<8*784, 256, 0, stream>>>(src, dst, fill_ptr, ssrc);
  k_wprep<<<(256*256 + 256*512 + 128*256)/256, 256, 0, stream>>>(Wl0,Wr0,Wl1,Wr1,Wl2,Wr2,W1t,W2t,W3t);
  k_xconv<<<(NN*128/4 + 255)/256, 256, 0, stream>>>(x, xb, xb8);

  // layer 1: agg(x) via fp8 table, then h1 = relu([agg1|x] @ W1t + b0)  (+ h1 fp8 copy)
  k_agg8<128,2><<<(NN+3)/4, 256, 0, stream>>>(xb8, row_start, cnt, rdeg, ssrc, agg1);
  k_gemm<true><<<782*2, 256, 0, stream>>>(agg1, 128, xb, 128, W1t, b0, h1, 256, nullptr, h1f8);

  // layer 2: agg(h1) via fp8 table, then h2 = relu([agg2|h1] @ W2t + b1)
  k_agg8<256,4><<<(NN+3)/4, 256, 0, stream>>>(h1f8, row_start, cnt, rdeg, ssrc, agg2);
  k_gemm<true><<<782*2, 256, 0, stream>>>(agg2, 256, h1, 256, W2t, b1, h2, 256, nullptr, nullptr);

  // layer 3: [Gl|Gr] = h2 @ [Wl2|pad|Wr2] (split write), then agg+root+b2+log_softmax
  k_gemm<false><<<782, 256, 0, stream>>>(h2, 256, h2, 0, W3t, nullptr, Gl, 64, Gr, nullptr);
  k_final<<<(NN+7)/8, 256, 0, stream>>>(Gl, Gr, row_start, cnt, rdeg, ssrc, b2, out);
}